// Round 1
// baseline (9360.046 us; speedup 1.0000x reference)
//
#include <hip/hip_runtime.h>

#define B_   8
#define C_   128
#define HW_  128
#define KW_  9
#define KK_  (KW_*C_)      // 1152
#define WS_  1168          // padded LDS k-stride (elements), multiple of 8
#define NB_PER_BATCH 4
#define GRID_MAIN 32

typedef __bf16 bf16x8 __attribute__((ext_vector_type(8)));
typedef float  floatx4 __attribute__((ext_vector_type(4)));

__device__ __forceinline__ unsigned short bf16rn(float f) {
  union { float f; unsigned u; } x; x.f = f;
  unsigned r = (x.u + 0x7fffu + ((x.u >> 16) & 1u)) >> 16;
  return (unsigned short)r;
}

// ---------------- prologue: x (B,C,H,W) -> y (B,H,W,C) fp32 + bf16 shadow ----
__global__ __launch_bounds__(256) void nchw_to_nhwc(const float* __restrict__ x,
                                                    float* __restrict__ y,
                                                    unsigned short* __restrict__ yb) {
  __shared__ float tile[32][33];
  const int blk = blockIdx.x;
  const int b = blk >> 7, h = blk & 127;
  const int tx = threadIdx.x & 31, ty = threadIdx.x >> 5; // ty 0..7
  for (int t = 0; t < 16; ++t) {
    const int c0 = (t >> 2) * 32, w0 = (t & 3) * 32;
#pragma unroll
    for (int i = 0; i < 4; ++i) {
      const int c = c0 + ty + i * 8;
      tile[ty + i * 8][tx] = x[(((long)b * C_ + c) * HW_ + h) * HW_ + w0 + tx];
    }
    __syncthreads();
#pragma unroll
    for (int i = 0; i < 4; ++i) {
      const int w = w0 + ty + i * 8;
      const float v = tile[tx][ty + i * 8];
      const long o = (((long)b * HW_ + h) * HW_ + w) * C_ + c0 + tx;
      y[o] = v;
      yb[o] = bf16rn(v);
    }
    __syncthreads();
  }
}

// ---------------- epilogue: y (B,H,W,C) -> out (B,C,H,W) ---------------------
__global__ __launch_bounds__(256) void nhwc_to_nchw(const float* __restrict__ y,
                                                    float* __restrict__ out) {
  __shared__ float tile[32][33];
  const int blk = blockIdx.x;
  const int b = blk >> 7, h = blk & 127;
  const int tx = threadIdx.x & 31, ty = threadIdx.x >> 5;
  for (int t = 0; t < 16; ++t) {
    const int w0 = (t >> 2) * 32, c0 = (t & 3) * 32;
#pragma unroll
    for (int i = 0; i < 4; ++i) {
      const int w = w0 + ty + i * 8;
      tile[ty + i * 8][tx] = y[(((long)b * HW_ + h) * HW_ + w) * C_ + c0 + tx];
    }
    __syncthreads();
#pragma unroll
    for (int i = 0; i < 4; ++i) {
      const int c = c0 + ty + i * 8;
      out[(((long)b * C_ + c) * HW_ + h) * HW_ + w0 + tx] = tile[tx][ty + i * 8];
    }
    __syncthreads();
  }
}

// ---------------- main persistent scan kernel --------------------------------
__global__ __launch_bounds__(256, 1) void scnn_scan(
    const float* __restrict__ kin0, const float* __restrict__ kin1,
    const float* __restrict__ kin2, const float* __restrict__ kin3,
    float* __restrict__ y, unsigned short* __restrict__ yb,
    unsigned* cnt, unsigned* done) {
  __shared__ unsigned short wlds[32 * WS_];
  const int tid = threadIdx.x;
  const int bid = blockIdx.x;
  const int batch = bid & 7;        // same-batch blocks share bid%8 -> same XCD
  const int chunk = bid >> 3;       // 0..3
  const int co0 = chunk * 32;
  const int lane = tid & 63;
  const int wave = tid >> 6;
  const int lrow = lane & 15;
  const int quad = lane >> 4;
  const int r0 = wave * 32;
  const long ybase = (long)batch * (HW_ * HW_ * C_);

  const float* kptr[4] = {kin0, kin1, kin2, kin3};
  const int ssA[4] = {HW_ * C_, HW_ * C_, C_, C_};
  const int srA[4] = {C_, C_, HW_ * C_, HW_ * C_};
  const int s0A[4] = {0, HW_ - 1, 0, HW_ - 1};
  const int dsA[4] = {1, -1, 1, -1};

  for (int dir = 0; dir < 4; ++dir) {
    // stage this chunk's weights, transposed co-major: wlds[co][kw*128+ci]
    const float* Kg = kptr[dir];
    for (int idx = tid; idx < 32 * KK_; idx += 256) {
      const int col = idx & 31;     // co_local (fast for coalesced global read)
      const int kk = idx >> 5;      // kw*128+ci
      wlds[col * WS_ + kk] = bf16rn(Kg[(long)kk * C_ + co0 + col]);
    }
    __syncthreads();

    const int ss = ssA[dir], sr = srA[dir], s0 = s0A[dir], ds = dsA[dir];
    const int fbase = (dir * 8 + batch) * HW_;

    for (int step = 1; step < HW_; ++step) {
      const int s = s0 + step * ds;
      const int sp = s - ds;
      if (step > 1) {
        const unsigned* flag = &cnt[fbase + sp];
        while (__hip_atomic_load(flag, __ATOMIC_ACQUIRE, __HIP_MEMORY_SCOPE_AGENT) <
               NB_PER_BATCH) {
          __builtin_amdgcn_s_sleep(1);
        }
      }
      __threadfence();

      floatx4 acc00 = {0.f, 0.f, 0.f, 0.f}, acc01 = {0.f, 0.f, 0.f, 0.f};
      floatx4 acc10 = {0.f, 0.f, 0.f, 0.f}, acc11 = {0.f, 0.f, 0.f, 0.f};
      const unsigned short* ybp = yb + ybase + (long)sp * ss;
      const unsigned short* wl0 = &wlds[lrow * WS_];
      const unsigned short* wl1 = &wlds[(lrow + 16) * WS_];

#pragma unroll 1
      for (int kw = 0; kw < KW_; ++kw) {
        const int w0 = r0 + lrow + kw - 4;
        const int w1 = w0 + 16;
        const int w0c = w0 < 0 ? 0 : (w0 > HW_ - 1 ? HW_ - 1 : w0);
        const int w1c = w1 < 0 ? 0 : (w1 > HW_ - 1 ? HW_ - 1 : w1);
        const bool ok0 = (w0 == w0c), ok1 = (w1 == w1c);
        const unsigned short* pa0 = ybp + (long)w0c * sr + quad * 8;
        const unsigned short* pa1 = ybp + (long)w1c * sr + quad * 8;
        const int wk = kw * C_ + quad * 8;
#pragma unroll
        for (int c4 = 0; c4 < 4; ++c4) {
          bf16x8 a0 = *(const bf16x8*)(pa0 + c4 * 32);
          bf16x8 a1 = *(const bf16x8*)(pa1 + c4 * 32);
          const bf16x8 az = {};
          if (!ok0) a0 = az;
          if (!ok1) a1 = az;
          const bf16x8 b0 = *(const bf16x8*)(wl0 + wk + c4 * 32);
          const bf16x8 b1 = *(const bf16x8*)(wl1 + wk + c4 * 32);
          acc00 = __builtin_amdgcn_mfma_f32_16x16x32_bf16(a0, b0, acc00, 0, 0, 0);
          acc01 = __builtin_amdgcn_mfma_f32_16x16x32_bf16(a0, b1, acc01, 0, 0, 0);
          acc10 = __builtin_amdgcn_mfma_f32_16x16x32_bf16(a1, b0, acc10, 0, 0, 0);
          acc11 = __builtin_amdgcn_mfma_f32_16x16x32_bf16(a1, b1, acc11, 0, 0, 0);
        }
      }

      // epilogue: out = cur + relu(acc); write fp32 master + bf16 shadow
      float* yrow = y + ybase + (long)s * ss;
      unsigned short* ybrow = yb + ybase + (long)s * ss;
#pragma unroll
      for (int ti = 0; ti < 2; ++ti) {
#pragma unroll
        for (int tj = 0; tj < 2; ++tj) {
          const floatx4 a =
              (ti == 0) ? ((tj == 0) ? acc00 : acc01) : ((tj == 0) ? acc10 : acc11);
          const int co = co0 + tj * 16 + lrow;
#pragma unroll
          for (int rg = 0; rg < 4; ++rg) {
            const int r = r0 + ti * 16 + quad * 4 + rg;
            const long off = (long)r * sr + co;
            float v = a[rg];
            v = v > 0.f ? v : 0.f;
            const float o = yrow[off] + v;
            yrow[off] = o;
            ybrow[off] = bf16rn(o);
          }
        }
      }

      __threadfence();
      __syncthreads();
      if (tid == 0) {
        __hip_atomic_fetch_add(&cnt[fbase + s], 1u, __ATOMIC_RELEASE,
                               __HIP_MEMORY_SCOPE_AGENT);
      }
    }

    // direction barrier across all 32 blocks
    __threadfence();
    __syncthreads();
    if (tid == 0) {
      __hip_atomic_fetch_add(&done[dir], 1u, __ATOMIC_RELEASE,
                             __HIP_MEMORY_SCOPE_AGENT);
    }
    const unsigned* dp = &done[dir];
    while (__hip_atomic_load(dp, __ATOMIC_ACQUIRE, __HIP_MEMORY_SCOPE_AGENT) <
           GRID_MAIN) {
      __builtin_amdgcn_s_sleep(1);
    }
    __threadfence();
    __syncthreads();
  }
}

// ---------------- launcher ---------------------------------------------------
extern "C" void kernel_launch(void* const* d_in, const int* in_sizes, int n_in,
                              void* d_out, int out_size, void* d_ws, size_t ws_size,
                              hipStream_t stream) {
  const float* x   = (const float*)d_in[0];
  const float* ktd = (const float*)d_in[1];
  const float* kdt = (const float*)d_in[2];
  const float* klr = (const float*)d_in[3];
  const float* krl = (const float*)d_in[4];
  float* out = (float*)d_out;

  char* ws = (char*)d_ws;
  float* y = (float*)ws;                                   // 67,108,864 B
  unsigned short* yb = (unsigned short*)(ws + 67108864);   // 33,554,432 B
  unsigned* cnt = (unsigned*)(ws + 100663296);             // 16,384 B
  unsigned* done = (unsigned*)(ws + 100663296 + 16384);    // 16 B

  hipMemsetAsync(cnt, 0, 16384 + 64, stream);
  nchw_to_nhwc<<<B_ * HW_, 256, 0, stream>>>(x, y, yb);
  scnn_scan<<<GRID_MAIN, 256, 0, stream>>>(ktd, kdt, klr, krl, y, yb, cnt, done);
  nhwc_to_nchw<<<B_ * HW_, 256, 0, stream>>>(y, out);
}

// Round 2
// 8286.269 us; speedup vs baseline: 1.1296x; 1.1296x over previous
//
#include <hip/hip_runtime.h>

#define B_   8
#define C_   128
#define HW_  128
#define KW_  9
#define STRD 136                 // LDS pos stride in bf16 elems (2-way bank alias only)
#define NPOS 136                 // 4 zero-pad + 128 + 4 zero-pad
#define BUFE (NPOS * STRD)       // 18496 elems per buffer

typedef __bf16 bf16x8 __attribute__((ext_vector_type(8)));
typedef __bf16 bf16x4 __attribute__((ext_vector_type(4)));
typedef float  floatx4 __attribute__((ext_vector_type(4)));

__device__ __forceinline__ unsigned short bf16rn(float f) {
  union { float f; unsigned u; } x; x.f = f;
  return (unsigned short)((x.u + 0x7fffu + ((x.u >> 16) & 1u)) >> 16);
}

// ---------------- prologue: x (B,C,H,W) -> y (B,H,W,C) fp32 ------------------
__global__ __launch_bounds__(256) void nchw_to_nhwc(const float* __restrict__ x,
                                                    float* __restrict__ y) {
  __shared__ float tile[32][33];
  const int blk = blockIdx.x;
  const int b = blk >> 7, h = blk & 127;
  const int tx = threadIdx.x & 31, ty = threadIdx.x >> 5;
  for (int t = 0; t < 16; ++t) {
    const int c0 = (t >> 2) * 32, w0 = (t & 3) * 32;
#pragma unroll
    for (int i = 0; i < 4; ++i) {
      const int c = c0 + ty + i * 8;
      tile[ty + i * 8][tx] = x[(((long)b * C_ + c) * HW_ + h) * HW_ + w0 + tx];
    }
    __syncthreads();
#pragma unroll
    for (int i = 0; i < 4; ++i) {
      const int w = w0 + ty + i * 8;
      y[(((long)b * HW_ + h) * HW_ + w) * C_ + c0 + tx] = tile[tx][ty + i * 8];
    }
    __syncthreads();
  }
}

// ---------------- epilogue: y (B,H,W,C) -> out (B,C,H,W) ---------------------
__global__ __launch_bounds__(256) void nhwc_to_nchw(const float* __restrict__ y,
                                                    float* __restrict__ out) {
  __shared__ float tile[32][33];
  const int blk = blockIdx.x;
  const int b = blk >> 7, h = blk & 127;
  const int tx = threadIdx.x & 31, ty = threadIdx.x >> 5;
  for (int t = 0; t < 16; ++t) {
    const int w0 = (t >> 2) * 32, c0 = (t & 3) * 32;
#pragma unroll
    for (int i = 0; i < 4; ++i) {
      const int w = w0 + ty + i * 8;
      tile[ty + i * 8][tx] = y[(((long)b * HW_ + h) * HW_ + w) * C_ + c0 + tx];
    }
    __syncthreads();
#pragma unroll
    for (int i = 0; i < 4; ++i) {
      const int c = c0 + ty + i * 8;
      out[(((long)b * C_ + c) * HW_ + h) * HW_ + w0 + tx] = tile[tx][ty + i * 8];
    }
    __syncthreads();
  }
}

// ---------------- main scan: one block per batch, zero cross-block sync ------
__global__ __launch_bounds__(256, 1) void scnn_scan(
    const float* __restrict__ k0, const float* __restrict__ k1,
    const float* __restrict__ k2, const float* __restrict__ k3,
    float* __restrict__ y) {
  __shared__ unsigned short prow[2][BUFE];
  const int tid = threadIdx.x;
  const int b = blockIdx.x;
  const int lane = tid & 63;
  const int wave = tid >> 6;
  const int l15 = lane & 15;
  const int quad = lane >> 4;
  const int ybase = b * (HW_ * HW_ * C_);

  // zero both LDS buffers once (pads must read as 0 for conv zero-padding)
  {
    unsigned long long* p = (unsigned long long*)&prow[0][0];
    for (int i = tid; i < 2 * BUFE / 4; i += 256) p[i] = 0ull;
  }
  __syncthreads();

  for (int dir = 0; dir < 4; ++dir) {
    const float* Kg = (dir == 0) ? k0 : (dir == 1) ? k1 : (dir == 2) ? k2 : k3;
    const int posStride = (dir < 2) ? C_ : HW_ * C_;  // stride between conv positions
    const int sStride   = (dir < 2) ? HW_ * C_ : C_;  // stride between scan rows
    const int s0 = (dir & 1) ? HW_ - 1 : 0;
    const int ds = (dir & 1) ? -1 : 1;

    // ---- persistent weight fragments in VGPRs: A-operand (m = co) ----------
    // wfrag[kw][ci-block][co-tile]: elem j = K[kw][ci4*32+quad*8+j][wave*32+ct*16+l15]
    bf16x8 wfrag[KW_][4][2];
#pragma unroll
    for (int kw = 0; kw < KW_; ++kw)
#pragma unroll
      for (int c4 = 0; c4 < 4; ++c4)
#pragma unroll
        for (int ct = 0; ct < 2; ++ct) {
          union { bf16x8 v; unsigned short u[8]; } t;
#pragma unroll
          for (int j = 0; j < 8; ++j)
            t.u[j] = bf16rn(Kg[(kw * 128 + c4 * 32 + quad * 8 + j) * 128 +
                               wave * 32 + ct * 16 + l15]);
          wfrag[kw][c4][ct] = t.v;
        }

    // ---- init LDS with first row (it is already final output of this dir) --
    for (int i = tid; i < (HW_ * C_) / 4; i += 256) {
      const int pos = i >> 5;
      const int c = (i & 31) << 2;
      const floatx4 v =
          *(const floatx4*)&y[ybase + s0 * sStride + pos * posStride + c];
      union { bf16x4 h; unsigned short u[4]; } t;
      t.u[0] = bf16rn(v[0]); t.u[1] = bf16rn(v[1]);
      t.u[2] = bf16rn(v[2]); t.u[3] = bf16rn(v[3]);
      *(bf16x4*)&prow[0][(pos + 4) * STRD + c] = t.h;
    }
    __syncthreads();

    int pb = 0;
#pragma unroll 1
    for (int step = 1; step < HW_; ++step) {
      const int s = s0 + step * ds;
      const unsigned short* prev = prow[pb];
      unsigned short* nxt = prow[pb ^ 1];
      const int rowb = ybase + s * sStride;

      // cur-row loads issued early; latency hidden under the k-loop
      floatx4 cur[2][8];
#pragma unroll
      for (int ct = 0; ct < 2; ++ct)
#pragma unroll
        for (int n = 0; n < 8; ++n) {
          const int pos = n * 16 + l15;
          const int co = wave * 32 + ct * 16 + quad * 4;
          cur[ct][n] = *(const floatx4*)&y[rowb + pos * posStride + co];
        }

      floatx4 acc[2][8];
#pragma unroll
      for (int ct = 0; ct < 2; ++ct)
#pragma unroll
        for (int n = 0; n < 8; ++n) acc[ct][n] = floatx4{0.f, 0.f, 0.f, 0.f};

      // single address register + compile-time ds offsets for all 288 reads
      const unsigned short* pbase = prev + l15 * STRD + quad * 8;
#pragma unroll
      for (int kw = 0; kw < KW_; ++kw)
#pragma unroll
        for (int c4 = 0; c4 < 4; ++c4) {
          bf16x8 act[8];
#pragma unroll
          for (int n = 0; n < 8; ++n)
            act[n] = *(const bf16x8*)(pbase + (n * 16 + kw) * STRD + c4 * 32);
#pragma unroll
          for (int n = 0; n < 8; ++n) {
            acc[0][n] = __builtin_amdgcn_mfma_f32_16x16x32_bf16(
                wfrag[kw][c4][0], act[n], acc[0][n], 0, 0, 0);
            acc[1][n] = __builtin_amdgcn_mfma_f32_16x16x32_bf16(
                wfrag[kw][c4][1], act[n], acc[1][n], 0, 0, 0);
          }
        }

      // epilogue: out = cur + relu(acc); fp32 -> global, bf16 -> next LDS buf
#pragma unroll
      for (int ct = 0; ct < 2; ++ct)
#pragma unroll
        for (int n = 0; n < 8; ++n) {
          const int pos = n * 16 + l15;
          const int co = wave * 32 + ct * 16 + quad * 4;
          const floatx4 a = acc[ct][n];
          const floatx4 c = cur[ct][n];
          floatx4 o;
          o[0] = c[0] + (a[0] > 0.f ? a[0] : 0.f);
          o[1] = c[1] + (a[1] > 0.f ? a[1] : 0.f);
          o[2] = c[2] + (a[2] > 0.f ? a[2] : 0.f);
          o[3] = c[3] + (a[3] > 0.f ? a[3] : 0.f);
          *(floatx4*)&y[rowb + pos * posStride + co] = o;
          union { bf16x4 h; unsigned short u[4]; } t;
          t.u[0] = bf16rn(o[0]); t.u[1] = bf16rn(o[1]);
          t.u[2] = bf16rn(o[2]); t.u[3] = bf16rn(o[3]);
          *(bf16x4*)&nxt[(pos + 4) * STRD + co] = t.h;
        }
      __syncthreads();
      pb ^= 1;
    }
    __syncthreads();
  }
}

// ---------------- launcher ---------------------------------------------------
extern "C" void kernel_launch(void* const* d_in, const int* in_sizes, int n_in,
                              void* d_out, int out_size, void* d_ws, size_t ws_size,
                              hipStream_t stream) {
  const float* x   = (const float*)d_in[0];
  const float* ktd = (const float*)d_in[1];
  const float* kdt = (const float*)d_in[2];
  const float* klr = (const float*)d_in[3];
  const float* krl = (const float*)d_in[4];
  float* out = (float*)d_out;

  float* y = (float*)d_ws;  // 67,108,864 B running NHWC plane

  nchw_to_nhwc<<<B_ * HW_, 256, 0, stream>>>(x, y);
  scnn_scan<<<B_, 256, 0, stream>>>(ktd, kdt, klr, krl, y);
  nhwc_to_nchw<<<B_ * HW_, 256, 0, stream>>>(y, out);
}

// Round 3
// 5880.721 us; speedup vs baseline: 1.5916x; 1.4091x over previous
//
#include <hip/hip_runtime.h>

#define B_   8
#define C_   128
#define HW_  128
#define KW_  9
#define STRD 136                 // LDS pos stride in bf16 elems (17 granules/row -> rotated banks)
#define NPOS 136                 // 4 zero-pad + 128 + 4 zero-pad
#define BUFE (NPOS * STRD)       // 18496 elems per buffer
#define THREADS 512

typedef __bf16 bf16x8 __attribute__((ext_vector_type(8)));
typedef __bf16 bf16x4 __attribute__((ext_vector_type(4)));
typedef float  floatx4 __attribute__((ext_vector_type(4)));

__device__ __forceinline__ unsigned short bf16rn(float f) {
  union { float f; unsigned u; } x; x.f = f;
  return (unsigned short)((x.u + 0x7fffu + ((x.u >> 16) & 1u)) >> 16);
}

// ---------------- prologue: x (B,C,H,W) -> y (B,H,W,C) fp32 ------------------
__global__ __launch_bounds__(256) void nchw_to_nhwc(const float* __restrict__ x,
                                                    float* __restrict__ y) {
  __shared__ float tile[32][33];
  const int blk = blockIdx.x;
  const int b = blk >> 7, h = blk & 127;
  const int tx = threadIdx.x & 31, ty = threadIdx.x >> 5;
  for (int t = 0; t < 16; ++t) {
    const int c0 = (t >> 2) * 32, w0 = (t & 3) * 32;
#pragma unroll
    for (int i = 0; i < 4; ++i) {
      const int c = c0 + ty + i * 8;
      tile[ty + i * 8][tx] = x[(((long)b * C_ + c) * HW_ + h) * HW_ + w0 + tx];
    }
    __syncthreads();
#pragma unroll
    for (int i = 0; i < 4; ++i) {
      const int w = w0 + ty + i * 8;
      y[(((long)b * HW_ + h) * HW_ + w) * C_ + c0 + tx] = tile[tx][ty + i * 8];
    }
    __syncthreads();
  }
}

// ---------------- epilogue: y (B,H,W,C) -> out (B,C,H,W) ---------------------
__global__ __launch_bounds__(256) void nhwc_to_nchw(const float* __restrict__ y,
                                                    float* __restrict__ out) {
  __shared__ float tile[32][33];
  const int blk = blockIdx.x;
  const int b = blk >> 7, h = blk & 127;
  const int tx = threadIdx.x & 31, ty = threadIdx.x >> 5;
  for (int t = 0; t < 16; ++t) {
    const int w0 = (t >> 2) * 32, c0 = (t & 3) * 32;
#pragma unroll
    for (int i = 0; i < 4; ++i) {
      const int w = w0 + ty + i * 8;
      tile[ty + i * 8][tx] = y[(((long)b * HW_ + h) * HW_ + w) * C_ + c0 + tx];
    }
    __syncthreads();
#pragma unroll
    for (int i = 0; i < 4; ++i) {
      const int c = c0 + ty + i * 8;
      out[(((long)b * C_ + c) * HW_ + h) * HW_ + w0 + tx] = tile[tx][ty + i * 8];
    }
    __syncthreads();
  }
}

// ---------------- main scan: one block per batch, 8 waves, co16/wave ---------
// Register budget per wave: wfrag 144 + acc 32 + act staging ~48 + addr ~20
// = ~244 < 256 (2 waves/SIMD) -> no scratch spill, latency hiding across waves.
__global__ __launch_bounds__(THREADS, 2) void scnn_scan(
    const float* __restrict__ k0, const float* __restrict__ k1,
    const float* __restrict__ k2, const float* __restrict__ k3,
    float* __restrict__ y) {
  __shared__ unsigned short prow[2][BUFE];
  const int tid = threadIdx.x;
  const int b = blockIdx.x;
  const int lane = tid & 63;
  const int wave = tid >> 6;          // 0..7
  const int l15 = lane & 15;
  const int quad = lane >> 4;
  const int co0 = wave * 16;          // 16-co strip per wave
  const int ybase = b * (HW_ * HW_ * C_);

  // zero both LDS buffers once (halo rows must read as 0)
  {
    unsigned long long* p = (unsigned long long*)&prow[0][0];
    for (int i = tid; i < 2 * BUFE / 4; i += THREADS) p[i] = 0ull;
  }
  __syncthreads();

  for (int dir = 0; dir < 4; ++dir) {
    const float* Kg = (dir == 0) ? k0 : (dir == 1) ? k1 : (dir == 2) ? k2 : k3;
    const int posStride = (dir < 2) ? C_ : HW_ * C_;
    const int sStride   = (dir < 2) ? HW_ * C_ : C_;
    const int s0 = (dir & 1) ? HW_ - 1 : 0;
    const int ds = (dir & 1) ? -1 : 1;

    // persistent weights, A-operand (m = co_local): 36 frags = 144 VGPRs
    // elem j = K[kw][c4*32+quad*8+j][co0+l15]
    bf16x8 wfrag[KW_][4];
#pragma unroll
    for (int kw = 0; kw < KW_; ++kw)
#pragma unroll
      for (int c4 = 0; c4 < 4; ++c4) {
        union { bf16x8 v; unsigned short u[8]; } t;
#pragma unroll
        for (int j = 0; j < 8; ++j)
          t.u[j] = bf16rn(Kg[(kw * 128 + c4 * 32 + quad * 8 + j) * 128 + co0 + l15]);
        wfrag[kw][c4] = t.v;
      }

    // init LDS buffer 0 with the first row (already final for this dir)
    for (int i = tid; i < (HW_ * C_) / 4; i += THREADS) {
      const int pos = i >> 5;
      const int c = (i & 31) << 2;
      const floatx4 v =
          *(const floatx4*)&y[ybase + s0 * sStride + pos * posStride + c];
      union { bf16x4 h; unsigned short u[4]; } t;
      t.u[0] = bf16rn(v[0]); t.u[1] = bf16rn(v[1]);
      t.u[2] = bf16rn(v[2]); t.u[3] = bf16rn(v[3]);
      *(bf16x4*)&prow[0][(pos + 4) * STRD + c] = t.h;
    }
    __syncthreads();

    int pb = 0;
#pragma unroll 1
    for (int step = 1; step < HW_; ++step) {
      const int s = s0 + step * ds;
      const unsigned short* prev = prow[pb];
      unsigned short* nxt = prow[pb ^ 1];
      const int rowb = ybase + s * sStride;

      floatx4 acc[8];
#pragma unroll
      for (int n = 0; n < 8; ++n) acc[n] = floatx4{0.f, 0.f, 0.f, 0.f};

      // B-operand acts from LDS: n = pos (col = l15), k = ci (quad*8+j)
      const unsigned short* pbase = prev + l15 * STRD + quad * 8;
#pragma unroll
      for (int kw = 0; kw < KW_; ++kw)
#pragma unroll
        for (int c4 = 0; c4 < 4; ++c4) {
#pragma unroll
          for (int n = 0; n < 8; ++n) {
            const bf16x8 a =
                *(const bf16x8*)(pbase + (n * 16 + kw) * STRD + c4 * 32);
            acc[n] = __builtin_amdgcn_mfma_f32_16x16x32_bf16(wfrag[kw][c4], a,
                                                             acc[n], 0, 0, 0);
          }
        }

      // epilogue: out = cur + relu(acc); fp32 -> global, bf16 -> next LDS buf
      // C/D layout: pos = n*16 + l15 (col), co_local = quad*4 + reg (row)
#pragma unroll
      for (int n = 0; n < 8; ++n) {
        const int pos = n * 16 + l15;
        const int co = co0 + quad * 4;
        const long gidx = (long)rowb + (long)pos * posStride + co;
        const floatx4 c = *(const floatx4*)&y[gidx];
        const floatx4 a = acc[n];
        floatx4 o;
        o[0] = c[0] + (a[0] > 0.f ? a[0] : 0.f);
        o[1] = c[1] + (a[1] > 0.f ? a[1] : 0.f);
        o[2] = c[2] + (a[2] > 0.f ? a[2] : 0.f);
        o[3] = c[3] + (a[3] > 0.f ? a[3] : 0.f);
        *(floatx4*)&y[gidx] = o;
        union { bf16x4 h; unsigned short u[4]; } t;
        t.u[0] = bf16rn(o[0]); t.u[1] = bf16rn(o[1]);
        t.u[2] = bf16rn(o[2]); t.u[3] = bf16rn(o[3]);
        *(bf16x4*)&nxt[(pos + 4) * STRD + co] = t.h;
      }
      __syncthreads();
      pb ^= 1;
    }
    __syncthreads();
  }
}

// ---------------- launcher ---------------------------------------------------
extern "C" void kernel_launch(void* const* d_in, const int* in_sizes, int n_in,
                              void* d_out, int out_size, void* d_ws, size_t ws_size,
                              hipStream_t stream) {
  const float* x   = (const float*)d_in[0];
  const float* ktd = (const float*)d_in[1];
  const float* kdt = (const float*)d_in[2];
  const float* klr = (const float*)d_in[3];
  const float* krl = (const float*)d_in[4];
  float* out = (float*)d_out;

  float* y = (float*)d_ws;  // 67,108,864 B running NHWC plane

  nchw_to_nhwc<<<B_ * HW_, 256, 0, stream>>>(x, y);
  scnn_scan<<<B_, THREADS, 0, stream>>>(ktd, kdt, klr, krl, y);
  nhwc_to_nchw<<<B_ * HW_, 256, 0, stream>>>(y, out);
}

// Round 4
// 2481.885 us; speedup vs baseline: 3.7713x; 2.3695x over previous
//
#include <hip/hip_runtime.h>

#define B_   8
#define C_   128
#define HW_  128
#define KW_  9
#define BLKS 4               // blocks per batch (pos split)
#define POSB 32              // positions per block
#define ROWS 40              // 4 halo + 32 own + 4 halo
#define STRD 136             // LDS pos stride (elems)
#define BUFE (ROWS * STRD)   // 5440 elems per buffer
#define THREADS 512

typedef __bf16 bf16x8 __attribute__((ext_vector_type(8)));
typedef float  floatx4 __attribute__((ext_vector_type(4)));
typedef unsigned long long u64;

__device__ __forceinline__ unsigned short bf16rn(float f) {
  union { float f; unsigned u; } x; x.f = f;
  return (unsigned short)((x.u + 0x7fffu + ((x.u >> 16) & 1u)) >> 16);
}

// ---------------- prologue: x (B,C,H,W) -> y (B,H,W,C) fp32 ------------------
__global__ __launch_bounds__(256) void nchw_to_nhwc(const float* __restrict__ x,
                                                    float* __restrict__ y) {
  __shared__ float tile[32][33];
  const int blk = blockIdx.x;
  const int b = blk >> 7, h = blk & 127;
  const int tx = threadIdx.x & 31, ty = threadIdx.x >> 5;
  for (int t = 0; t < 16; ++t) {
    const int c0 = (t >> 2) * 32, w0 = (t & 3) * 32;
#pragma unroll
    for (int i = 0; i < 4; ++i) {
      const int c = c0 + ty + i * 8;
      tile[ty + i * 8][tx] = x[(((long)b * C_ + c) * HW_ + h) * HW_ + w0 + tx];
    }
    __syncthreads();
#pragma unroll
    for (int i = 0; i < 4; ++i) {
      const int w = w0 + ty + i * 8;
      y[(((long)b * HW_ + h) * HW_ + w) * C_ + c0 + tx] = tile[tx][ty + i * 8];
    }
    __syncthreads();
  }
}

// ---------------- epilogue: y (B,H,W,C) -> out (B,C,H,W) ---------------------
__global__ __launch_bounds__(256) void nhwc_to_nchw(const float* __restrict__ y,
                                                    float* __restrict__ out) {
  __shared__ float tile[32][33];
  const int blk = blockIdx.x;
  const int b = blk >> 7, h = blk & 127;
  const int tx = threadIdx.x & 31, ty = threadIdx.x >> 5;
  for (int t = 0; t < 16; ++t) {
    const int w0 = (t >> 2) * 32, c0 = (t & 3) * 32;
#pragma unroll
    for (int i = 0; i < 4; ++i) {
      const int w = w0 + ty + i * 8;
      tile[ty + i * 8][tx] = y[(((long)b * HW_ + h) * HW_ + w) * C_ + c0 + tx];
    }
    __syncthreads();
#pragma unroll
    for (int i = 0; i < 4; ++i) {
      const int c = c0 + ty + i * 8;
      out[(((long)b * C_ + c) * HW_ + h) * HW_ + w0 + tx] = tile[tx][ty + i * 8];
    }
    __syncthreads();
  }
}

// ---------------- per-direction scan: 32 blocks = 8 batch x 4 pos-chunks -----
// Halo/flags via RELAXED agent atomics only (cache-bypass; no buffer_inv/wbl2).
// Visibility: __syncthreads drains vmcnt(0) -> mailbox stores are at the
// coherence point before tid0's relaxed flag store.
__global__ __launch_bounds__(THREADS, 2) void scnn_scan_dir(
    const float* __restrict__ Kg, float* __restrict__ y,
    int* flags, u64* mb,
    const int posStride, const int sStride, const int s0, const int ds,
    const int dirIdx) {
  __shared__ unsigned short prow[2][BUFE];
  const int tid = threadIdx.x;
  const int bid = blockIdx.x;
  const int batch = bid & 7;
  const int blk = bid >> 3;
  const int p0 = blk * POSB;
  const int lane = tid & 63;
  const int wave = tid >> 6;
  const int l15 = lane & 15;
  const int quad = lane >> 4;
  const int co0 = wave * 16;
  const int ybase = batch * (HW_ * HW_ * C_);
  int* flagB = flags + (dirIdx * 8 + batch) * BLKS;

  // zero both LDS buffers (halo rows must read 0 for zero-pad conv)
  for (int i = tid; i < 2 * BUFE / 4; i += THREADS)
    ((u64*)prow)[i] = 0ull;

  // persistent weights, A-operand (m = co_local): 36 frags = 144 VGPRs
  bf16x8 wfrag[KW_][4];
#pragma unroll
  for (int kw = 0; kw < KW_; ++kw)
#pragma unroll
    for (int c4 = 0; c4 < 4; ++c4) {
      union { bf16x8 v; unsigned short u[8]; } t;
#pragma unroll
      for (int j = 0; j < 8; ++j)
        t.u[j] = bf16rn(Kg[(kw * 128 + c4 * 32 + quad * 8 + j) * 128 + co0 + l15]);
      wfrag[kw][c4] = t.v;
    }
  __syncthreads();

  // init: load first row (s0) 40-pos window (incl halo) from y -> buffer 0
  for (int i = tid; i < ROWS * 32; i += THREADS) {
    const int row = i >> 5, cg = i & 31;
    const int pos = p0 - 4 + row;
    if (pos >= 0 && pos < HW_) {
      const floatx4 v =
          *(const floatx4*)&y[ybase + s0 * sStride + pos * posStride + cg * 4];
      union { u64 u; unsigned short s[4]; } t;
      t.s[0] = bf16rn(v[0]); t.s[1] = bf16rn(v[1]);
      t.s[2] = bf16rn(v[2]); t.s[3] = bf16rn(v[3]);
      *(u64*)&prow[0][row * STRD + cg * 4] = t.u;
    }
  }
  __syncthreads();

  int pb = 0;
#pragma unroll 1
  for (int s = 1; s < HW_; ++s) {
    const int srow = s0 + s * ds;
    const int rowb = ybase + srow * sStride;

    __syncthreads();  // A: drains vmcnt -> step s-1 stores (incl mailbox) visible
    if (tid == 0)
      __hip_atomic_store(&flagB[blk], s - 1, __ATOMIC_RELAXED,
                         __HIP_MEMORY_SCOPE_AGENT);
    if (s >= 2) {
      if (tid == 0 && blk > 0)
        while (__hip_atomic_load(&flagB[blk - 1], __ATOMIC_RELAXED,
                                 __HIP_MEMORY_SCOPE_AGENT) < s - 1)
          __builtin_amdgcn_s_sleep(1);
      if (tid == 1 && blk < BLKS - 1)
        while (__hip_atomic_load(&flagB[blk + 1], __ATOMIC_RELAXED,
                                 __HIP_MEMORY_SCOPE_AGENT) < s - 1)
          __builtin_amdgcn_s_sleep(1);
      __syncthreads();  // P: poll done
      __atomic_signal_fence(__ATOMIC_SEQ_CST);
      const int par = (s - 1) & 1;
      if (tid < 256) {
        const int side = tid >> 7, p = (tid >> 5) & 3, cg = tid & 31;
        const bool doit = side ? (blk < BLKS - 1) : (blk > 0);
        if (doit) {
          const int srcB = side ? (blk + 1) : (blk - 1);
          const int srcSide = side ? 0 : 1;  // right halo = right nbr's L edge
          const int mbi =
              ((((batch * BLKS + srcB) * 2 + srcSide) * 2 + par) * 4 + p) * 32 + cg;
          const u64 v =
              __hip_atomic_load(&mb[mbi], __ATOMIC_RELAXED, __HIP_MEMORY_SCOPE_AGENT);
          const int row = side ? (36 + p) : p;
          *(u64*)&prow[pb][row * STRD + cg * 4] = v;
        }
      }
    }
    __syncthreads();  // B: halo in LDS; prev buffer complete

    // cur-row prefetch (independent of prev row; overlaps the k-loop)
    floatx4 cur[2];
#pragma unroll
    for (int n = 0; n < 2; ++n)
      cur[n] = *(const floatx4*)&y[rowb + (p0 + n * 16 + l15) * posStride +
                                   co0 + quad * 4];

    floatx4 acc[2];
    acc[0] = floatx4{0.f, 0.f, 0.f, 0.f};
    acc[1] = floatx4{0.f, 0.f, 0.f, 0.f};
    const unsigned short* pbase = &prow[pb][l15 * STRD + quad * 8];
#pragma unroll
    for (int kw = 0; kw < KW_; ++kw)
#pragma unroll
      for (int c4 = 0; c4 < 4; ++c4) {
        const bf16x8 a0 = *(const bf16x8*)(pbase + kw * STRD + c4 * 32);
        const bf16x8 a1 = *(const bf16x8*)(pbase + (kw + 16) * STRD + c4 * 32);
        acc[0] = __builtin_amdgcn_mfma_f32_16x16x32_bf16(wfrag[kw][c4], a0,
                                                         acc[0], 0, 0, 0);
        acc[1] = __builtin_amdgcn_mfma_f32_16x16x32_bf16(wfrag[kw][c4], a1,
                                                         acc[1], 0, 0, 0);
      }

    // epilogue: o = cur + relu(acc); fp32 -> y, bf16 -> nxt LDS (+ mailbox)
    unsigned short* nxt = prow[pb ^ 1];
    const int par_w = s & 1;
#pragma unroll
    for (int n = 0; n < 2; ++n) {
      const int pl = n * 16 + l15;           // local pos 0..31
      const int co = co0 + quad * 4;
      const floatx4 a = acc[n];
      const floatx4 c = cur[n];
      floatx4 o;
      o[0] = c[0] + (a[0] > 0.f ? a[0] : 0.f);
      o[1] = c[1] + (a[1] > 0.f ? a[1] : 0.f);
      o[2] = c[2] + (a[2] > 0.f ? a[2] : 0.f);
      o[3] = c[3] + (a[3] > 0.f ? a[3] : 0.f);
      *(floatx4*)&y[rowb + (p0 + pl) * posStride + co] = o;
      union { u64 u; unsigned short s[4]; } t;
      t.s[0] = bf16rn(o[0]); t.s[1] = bf16rn(o[1]);
      t.s[2] = bf16rn(o[2]); t.s[3] = bf16rn(o[3]);
      *(u64*)&nxt[(pl + 4) * STRD + co] = t.u;
      // boundary pos -> mailbox (relaxed agent atomics, bypass path)
      if (n == 0 && l15 < 4 && blk > 0) {
        const int mbi =
            ((((batch * BLKS + blk) * 2 + 0) * 2 + par_w) * 4 + l15) * 32 +
            (wave * 4 + quad);
        __hip_atomic_store(&mb[mbi], t.u, __ATOMIC_RELAXED,
                           __HIP_MEMORY_SCOPE_AGENT);
      }
      if (n == 1 && l15 >= 12 && blk < BLKS - 1) {
        const int mbi =
            ((((batch * BLKS + blk) * 2 + 1) * 2 + par_w) * 4 + (l15 - 12)) * 32 +
            (wave * 4 + quad);
        __hip_atomic_store(&mb[mbi], t.u, __ATOMIC_RELAXED,
                           __HIP_MEMORY_SCOPE_AGENT);
      }
    }
    pb ^= 1;
  }
}

// ---------------- launcher ---------------------------------------------------
extern "C" void kernel_launch(void* const* d_in, const int* in_sizes, int n_in,
                              void* d_out, int out_size, void* d_ws, size_t ws_size,
                              hipStream_t stream) {
  const float* x = (const float*)d_in[0];
  const float* K[4] = {(const float*)d_in[1], (const float*)d_in[2],
                       (const float*)d_in[3], (const float*)d_in[4]};
  float* out = (float*)d_out;

  char* ws = (char*)d_ws;
  float* y = (float*)ws;                       // 67,108,864 B
  int* flags = (int*)(ws + 67108864);          // 4*8*4 ints = 512 B
  u64* mb = (u64*)(ws + 67108864 + 1024);      // 8*4*2*2*4*128 bf16 = 262144 B

  hipMemsetAsync(flags, 0, 1024, stream);
  nchw_to_nhwc<<<B_ * HW_, 256, 0, stream>>>(x, y);

  const int PS[4] = {C_, C_, HW_ * C_, HW_ * C_};
  const int SS[4] = {HW_ * C_, HW_ * C_, C_, C_};
  const int S0[4] = {0, HW_ - 1, 0, HW_ - 1};
  const int DS[4] = {1, -1, 1, -1};
  for (int d = 0; d < 4; ++d)
    scnn_scan_dir<<<B_ * BLKS, THREADS, 0, stream>>>(K[d], y, flags, mb, PS[d],
                                                     SS[d], S0[d], DS[d], d);

  nhwc_to_nchw<<<B_ * HW_, 256, 0, stream>>>(y, out);
}